// Round 9
// baseline (9334.904 us; speedup 1.0000x reference)
//
#include <hip/hip_runtime.h>
#include <hip/hip_bf16.h>
#include <cstdint>
#include <cstddef>

typedef __bf16 bf16_t;
typedef __bf16 bf16x8 __attribute__((ext_vector_type(8)));
typedef float  f32x4  __attribute__((ext_vector_type(4)));

#define TOKENS 16384
#define HIDDEN 2048
#define FFN    8192

__device__ __forceinline__ void gload_lds16(const bf16_t* g, bf16_t* l) {
    __builtin_amdgcn_global_load_lds((const __attribute__((address_space(1))) void*)g,
                                     (__attribute__((address_space(3))) void*)l,
                                     16, 0, 0);
}

__global__ void cvt_f32_to_bf16(const float* __restrict__ in, bf16_t* __restrict__ out, int n8) {
    int i = blockIdx.x * blockDim.x + threadIdx.x;
    if (i >= n8) return;
    size_t base = (size_t)i * 8;
    f32x4 v0 = *(const f32x4*)&in[base];
    f32x4 v1 = *(const f32x4*)&in[base + 4];
    bf16x8 o;
    o[0] = (bf16_t)v0[0]; o[1] = (bf16_t)v0[1]; o[2] = (bf16_t)v0[2]; o[3] = (bf16_t)v0[3];
    o[4] = (bf16_t)v1[0]; o[5] = (bf16_t)v1[1]; o[6] = (bf16_t)v1[2]; o[7] = (bf16_t)v1[3];
    *(bf16x8*)&out[base] = o;
}

__global__ void transpose_cvt(const float* __restrict__ src, bf16_t* __restrict__ dst,
                              int R, int C) {
    __shared__ bf16_t tile[64][66];
    const int tcols = C >> 6;
    const int bx = blockIdx.x % tcols;
    const int by = blockIdx.x / tcols;
    const int c0 = bx << 6, r0 = by << 6;
    const int t = threadIdx.x;
#pragma unroll
    for (int i = 0; i < 16; ++i) {
        int idx = i * 256 + t;
        int rr = idx >> 6, cc = idx & 63;
        tile[rr][cc] = (bf16_t)src[(size_t)(r0 + rr) * C + (c0 + cc)];
    }
    __syncthreads();
#pragma unroll
    for (int i = 0; i < 16; ++i) {
        int idx = i * 256 + t;
        int cc = idx >> 6, rr = idx & 63;
        dst[(size_t)(c0 + cc) * R + (r0 + rr)] = tile[rr][cc];
    }
}

// ---------------------------------------------------------------------------
// 256x256 8-phase GEMM, BK=32, 64KB LDS -> 2 workgroups/CU (4 waves/SIMD).
// EXACT half-scale isomorphism of the round-4 proven schedule (passed R4+R5):
// same phase order, same liveness slots, same swizzle; each half-tile is now
// 128 rows x 32 k = 8KB = ONE global_load_lds per thread.
//
// LDS elem map: A buf0 [0,8192) (A0/A1 at 0/4096), A buf1 [8192,16384);
//               B buf0 [16384,24576) (B0/B1), B buf1 [24576,32768).
// LIVENESS (per wave: its A-half read P1(QM0 rows0-63)+P3(QM1 rows64-127);
// its B-quarter read P1(QN0)+P2(QN1); mirrored P5-P7 on buf1):
//   buf.B free after P2/P6; buf.A free after P3/P7.
// STAGE slots (1 load each): P1:t1.A1 | P3:t2.B0 | P4:t2.B1,t2.A0 | P5:t2.A1
//   | P7:t3.B0 | P8:t3.B1,t3.A0   (each slot >=1 drained phase after the
//   region's last read, with a barrier between -- verified per slot)
// vmcnt ledger (1 load/STAGE): entry P1 = 3 outstanding (t1.A0,B0,B1);
//   P1:+1=4, P3:+1=5, P4:+2=7, VMW(3) retires 4 = all t1 -> P5 safe;
//   P5:+1=4, P7:+1=5, P8:+2=7, VMW(3) retires 4 = all t2 -> next P1 safe.
// ---------------------------------------------------------------------------
#define BAR() __builtin_amdgcn_s_barrier()
#define LGKM0() do { asm volatile("s_waitcnt lgkmcnt(0)" ::: "memory"); \
                     __builtin_amdgcn_sched_barrier(0); } while (0)
#define VMW(n) asm volatile("s_waitcnt vmcnt(" #n ")" ::: "memory")
#define PRIO1() __builtin_amdgcn_s_setprio(1)
#define PRIO0() __builtin_amdgcn_s_setprio(0)

#define DS_A(BUF, QM, AF) do { \
    _Pragma("unroll") for (int mf = 0; mf < 4; ++mf) \
        AF[mf] = *(const bf16x8*)&smem[(BUF)*8192 + wr*4096 + (((QM)*4+mf))*512 + lnb_e]; \
} while (0)

#define DS_Bm(BUF, QN, BB) do { \
    _Pragma("unroll") for (int nf = 0; nf < 2; ++nf) \
        BB[nf] = *(const bf16x8*)&smem[16384 + (BUF)*8192 + bhalf + (((QN)*2+nf))*512 + lnb_e]; \
} while (0)

#define MFMA_Q(QM, QN, AF, BB) do { \
    _Pragma("unroll") for (int mf = 0; mf < 4; ++mf) \
    _Pragma("unroll") for (int nf = 0; nf < 2; ++nf) \
        acc[(QM)*4+mf][(QN)*2+nf] = __builtin_amdgcn_mfma_f32_16x16x32_bf16( \
            AF[mf], BB[nf], acc[(QM)*4+mf][(QN)*2+nf], 0, 0, 0); \
} while (0)

// stage one half-tile (128 rows x 32 k = 4096 elems): 1 global_load_lds/thread
#define STAGE(GBASE, HROWS, TILE, EOFF) do { \
    gload_lds16((GBASE) + aoff0 + (size_t)(HROWS) * K + (TILE) * 32, \
                &smem[(EOFF) + wave * 512]); \
} while (0)

template<bool GELU_EPI, int M, int N, int K>
__global__ __launch_bounds__(512, 4)
void gemm32(const bf16_t* __restrict__ A, const bf16_t* __restrict__ BT,
            const float* __restrict__ bias, void* __restrict__ out)
{
    constexpr int BM = 256, BN = 256;
    constexpr int NT = K / 32, NI = NT / 2;
    constexpr int NBN = N / BN;
    __shared__ __align__(128) bf16_t smem[32768];   // 64 KiB

    const int t = threadIdx.x;
    const int wave = t >> 6, lane = t & 63;
    const int fr = lane & 15, fq = lane >> 4;
    const int wr = wave >> 2, wc = wave & 3;

    int wg = blockIdx.x;
    { const int cpx = (int)gridDim.x >> 3; wg = (wg & 7) * cpx + (wg >> 3); }
    const int bm = wg / NBN, bn = wg % NBN;
    const int rowA0 = bm * BM, colB0 = bn * BN;

    // staging source pre-swizzle (inverse st_16x32): LDS byte o within
    // half-tile -> row=(o>>10)*16 + ri, k=b>>1; ri=(o>>6)&15, b=(o&63)^((ri&8)<<2)
    int sr0, sk0;
    {
        int o = t * 16;
        int ri = (o >> 6) & 15;
        int b = (o & 63) ^ ((ri & 8) << 2);
        sr0 = (o >> 10) * 16 + ri;
        sk0 = b >> 1;
    }
    const bf16_t* gA0 = A + (size_t)rowA0 * K;
    const bf16_t* gB0 = BT + (size_t)colB0 * K;
    const size_t aoff0 = (size_t)sr0 * K + sk0;

    // read-side swizzled lane base (elements): row fr, k-chunk fq (unchanged
    // from the zero-conflict R4 pattern)
    const int lnb_e = fr * 32 + ((fq * 8) ^ ((fr & 8) << 1));
    const int bhalf = (wc >> 1) * 4096 + (wc & 1) * 2048;

    f32x4 acc[8][4] = {};
    bf16x8 afA[4], afB[4], b0[2], b1[2];

    // prologue: t0 fully + t1.A0/B0/B1; drain t0
    STAGE(gA0, 0,   0, 0);          // t0.A0
    STAGE(gA0, 128, 0, 4096);       // t0.A1
    STAGE(gB0, 0,   0, 16384);      // t0.B0
    STAGE(gB0, 128, 0, 20480);      // t0.B1
    STAGE(gA0, 0,   1, 8192);       // t1.A0
    STAGE(gB0, 0,   1, 24576);      // t1.B0
    STAGE(gB0, 128, 1, 28672);      // t1.B1
    VMW(3);                         // t0 landed; t1's 3 loads in flight
    BAR();

    for (int i = 0; i < NI - 1; ++i) {
        const int t1 = 2 * i + 1, t2 = 2 * i + 2, t3 = 2 * i + 3;
        // P1: Q00 on buf0
        DS_A(0, 0, afA); DS_Bm(0, 0, b0);
        STAGE(gA0, 128, t1, 12288);            // buf1.A1 <- t1.A1
        BAR(); LGKM0();
        PRIO1(); MFMA_Q(0, 0, afA, b0); PRIO0();
        BAR();
        // P2: Q01 (no stage; buf0.B live until end of P2)
        DS_Bm(0, 1, b1);
        BAR(); LGKM0();
        PRIO1(); MFMA_Q(0, 1, afA, b1); PRIO0();
        BAR();
        // P3: Q11 (buf0.B free after P2)
        DS_A(0, 1, afB);
        STAGE(gB0, 0, t2, 16384);              // buf0.B0 <- t2.B0
        BAR(); LGKM0();
        PRIO1(); MFMA_Q(1, 1, afB, b1); PRIO0();
        BAR();
        // P4: Q10 regs-only (buf0.A free after P3)
        STAGE(gB0, 128, t2, 20480);            // buf0.B1 <- t2.B1
        STAGE(gA0, 0,   t2, 0);                // buf0.A0 <- t2.A0
        VMW(3);                                // all t1 landed
        BAR();
        PRIO1(); MFMA_Q(1, 0, afB, b0); PRIO0();
        BAR();
        // P5: Q00 on buf1
        DS_A(1, 0, afA); DS_Bm(1, 0, b0);
        STAGE(gA0, 128, t2, 4096);             // buf0.A1 <- t2.A1
        BAR(); LGKM0();
        PRIO1(); MFMA_Q(0, 0, afA, b0); PRIO0();
        BAR();
        // P6: Q01
        DS_Bm(1, 1, b1);
        BAR(); LGKM0();
        PRIO1(); MFMA_Q(0, 1, afA, b1); PRIO0();
        BAR();
        // P7: Q11 (buf1.B free after P6)
        DS_A(1, 1, afB);
        STAGE(gB0, 0, t3, 24576);              // buf1.B0 <- t3.B0
        BAR(); LGKM0();
        PRIO1(); MFMA_Q(1, 1, afB, b1); PRIO0();
        BAR();
        // P8: Q10 (buf1.A free after P7)
        STAGE(gB0, 128, t3, 28672);            // buf1.B1 <- t3.B1
        STAGE(gA0, 0,   t3, 8192);             // buf1.A0 <- t3.A0
        VMW(3);                                // all t2 landed
        BAR();
        PRIO1(); MFMA_Q(1, 0, afB, b0); PRIO0();
        BAR();
    }

    // peeled last iteration: tiles NT-2 (buf0), NT-1 (buf1)
    DS_A(0, 0, afA); DS_Bm(0, 0, b0);
    STAGE(gA0, 128, NT - 1, 12288);            // buf1.A1 <- (NT-1).A1
    BAR(); LGKM0();
    PRIO1(); MFMA_Q(0, 0, afA, b0); PRIO0();
    BAR();
    DS_Bm(0, 1, b1);
    BAR(); LGKM0();
    PRIO1(); MFMA_Q(0, 1, afA, b1); PRIO0();
    BAR();
    DS_A(0, 1, afB);
    BAR(); LGKM0();
    PRIO1(); MFMA_Q(1, 1, afB, b1); PRIO0();
    BAR();
    VMW(0);                                    // last tile fully landed
    BAR();
    PRIO1(); MFMA_Q(1, 0, afB, b0); PRIO0();
    BAR();
    DS_A(1, 0, afA); DS_Bm(1, 0, b0);
    BAR(); LGKM0();
    PRIO1(); MFMA_Q(0, 0, afA, b0); PRIO0();
    BAR();
    DS_Bm(1, 1, b1);
    BAR(); LGKM0();
    PRIO1(); MFMA_Q(0, 1, afA, b1); PRIO0();
    BAR();
    DS_A(1, 1, afB);
    BAR(); LGKM0();
    PRIO1(); MFMA_Q(1, 1, afB, b1); PRIO0();
    LGKM0();
    PRIO1(); MFMA_Q(1, 0, afB, b0); PRIO0();

    // epilogue: C/D layout col=lane&15, row=(lane>>4)*4+reg
    const int orow = rowA0 + wr * 128 + fq * 4;
    const int ocol = colB0 + wc * 64 + fr;
#pragma unroll
    for (int mf = 0; mf < 8; ++mf) {
#pragma unroll
        for (int nf = 0; nf < 4; ++nf) {
            const int c = ocol + nf * 16;
            const float bv = bias[c];
#pragma unroll
            for (int v = 0; v < 4; ++v) {
                const int r = orow + mf * 16 + v;
                float xv = acc[mf][nf][v] + bv;
                if constexpr (GELU_EPI) {
                    float g = 0.5f * xv * (1.0f + erff(xv * 0.70710678118654752f));
                    ((bf16_t*)out)[(size_t)r * N + c] = (bf16_t)g;
                } else {
                    ((float*)out)[(size_t)r * N + c] = xv;
                }
            }
        }
    }
}

extern "C" void kernel_launch(void* const* d_in, const int* in_sizes, int n_in,
                              void* d_out, int out_size, void* d_ws, size_t ws_size,
                              hipStream_t stream) {
    const float* x  = (const float*)d_in[0];
    const float* w1 = (const float*)d_in[1];
    const float* b1 = (const float*)d_in[2];
    const float* w2 = (const float*)d_in[3];
    const float* b2 = (const float*)d_in[4];
    float* y = (float*)d_out;

    const size_t xb_elems  = (size_t)TOKENS * HIDDEN;
    const size_t w1t_elems = (size_t)FFN * HIDDEN;
    const size_t w2t_elems = (size_t)HIDDEN * FFN;
    const size_t h_elems   = (size_t)TOKENS * FFN;
    const size_t need = (xb_elems + w1t_elems + w2t_elems + h_elems) * sizeof(bf16_t);
    if (ws_size < need) return;

    char* ws = (char*)d_ws;
    bf16_t* xb  = (bf16_t*)ws;
    bf16_t* w1t = xb + xb_elems;
    bf16_t* w2t = w1t + w1t_elems;
    bf16_t* h   = w2t + w2t_elems;

    cvt_f32_to_bf16<<<(TOKENS * HIDDEN / 8 + 255) / 256, 256, 0, stream>>>(
        x, xb, TOKENS * HIDDEN / 8);
    transpose_cvt<<<(HIDDEN / 64) * (FFN / 64), 256, 0, stream>>>(w1, w1t, HIDDEN, FFN);
    transpose_cvt<<<(FFN / 64) * (HIDDEN / 64), 256, 0, stream>>>(w2, w2t, FFN, HIDDEN);

    gemm32<true, TOKENS, FFN, HIDDEN>
        <<<(TOKENS / 256) * (FFN / 256), 512, 0, stream>>>(xb, w1t, b1, h);
    gemm32<false, TOKENS, HIDDEN, FFN>
        <<<(TOKENS / 256) * (HIDDEN / 256), 512, 0, stream>>>(h, w2t, b2, y);
}

// Round 10
// 1146.631 us; speedup vs baseline: 8.1412x; 8.1412x over previous
//
#include <hip/hip_runtime.h>
#include <hip/hip_bf16.h>
#include <cstdint>
#include <cstddef>

typedef __bf16 bf16_t;
typedef __bf16 bf16x8 __attribute__((ext_vector_type(8)));
typedef float  f32x4  __attribute__((ext_vector_type(4)));

#define TOKENS 16384
#define HIDDEN 2048
#define FFN    8192

__device__ __forceinline__ void gload_lds16(const bf16_t* g, bf16_t* l) {
    __builtin_amdgcn_global_load_lds((const __attribute__((address_space(1))) void*)g,
                                     (__attribute__((address_space(3))) void*)l,
                                     16, 0, 0);
}

__global__ void cvt_f32_to_bf16(const float* __restrict__ in, bf16_t* __restrict__ out, int n8) {
    int i = blockIdx.x * blockDim.x + threadIdx.x;
    if (i >= n8) return;
    size_t base = (size_t)i * 8;
    f32x4 v0 = *(const f32x4*)&in[base];
    f32x4 v1 = *(const f32x4*)&in[base + 4];
    bf16x8 o;
    o[0] = (bf16_t)v0[0]; o[1] = (bf16_t)v0[1]; o[2] = (bf16_t)v0[2]; o[3] = (bf16_t)v0[3];
    o[4] = (bf16_t)v1[0]; o[5] = (bf16_t)v1[1]; o[6] = (bf16_t)v1[2]; o[7] = (bf16_t)v1[3];
    *(bf16x8*)&out[base] = o;
}

__global__ void transpose_cvt(const float* __restrict__ src, bf16_t* __restrict__ dst,
                              int R, int C) {
    __shared__ bf16_t tile[64][66];
    const int tcols = C >> 6;
    const int bx = blockIdx.x % tcols;
    const int by = blockIdx.x / tcols;
    const int c0 = bx << 6, r0 = by << 6;
    const int t = threadIdx.x;
#pragma unroll
    for (int i = 0; i < 16; ++i) {
        int idx = i * 256 + t;
        int rr = idx >> 6, cc = idx & 63;
        tile[rr][cc] = (bf16_t)src[(size_t)(r0 + rr) * C + (c0 + cc)];
    }
    __syncthreads();
#pragma unroll
    for (int i = 0; i < 16; ++i) {
        int idx = i * 256 + t;
        int cc = idx >> 6, rr = idx & 63;
        dst[(size_t)(c0 + cc) * R + (r0 + rr)] = tile[rr][cc];
    }
}

// ---------------------------------------------------------------------------
// 256x256 8-phase GEMM == round-4 proven kernel (passed R4+R5) with ONE
// delta: ds_reads rebalanced 12/4/8/0 -> 8/4/8/4 (m201's pattern).
// B0-for-the-next-consumed-tile is read in the previously-empty P4/P8 slot,
// AFTER Q10 consumes the old b0 (same registers; program-order WAR; no new
// register set -> no spill risk). Staging slots, vmcnt ledger, liveness,
// swizzle, wait discipline: byte-identical to R4.
//
// b0 lifetime: written prologue/P8-prev -> read Q00(P1), Q10(P4) -> rewritten
//   end-P4 with B0(t1) -> read Q00(P5), Q10(P8) -> rewritten end-P8.
// Read-validity: P4-end read targets buf1.B0; P4's VMW(6) just retired all
//   of t1; next overwrite of buf1.B0 is P7's stage, 3 barriers after this
//   read's drain (P5's lgkmcnt(0)). P8-end read targets buf0.B0 = t2.B0
//   (staged P3, retired by P8's VMW(6)). Prologue read after VMW(6)+BAR.
// vmcnt ledger (unchanged): entry P1 = 6 outstanding (t1.A0,B0,B1);
//   P1:+2=8, P3:+2=10, P4:+4=14, VMW(6) retires 8 = all t1;
//   P5:+2=8, P7:+2=10, P8:+4=14, VMW(6) retires 8 = all t2.
// ---------------------------------------------------------------------------
#define BAR() __builtin_amdgcn_s_barrier()
#define LGKM0() do { asm volatile("s_waitcnt lgkmcnt(0)" ::: "memory"); \
                     __builtin_amdgcn_sched_barrier(0); } while (0)
#define VMW(n) asm volatile("s_waitcnt vmcnt(" #n ")" ::: "memory")
#define PRIO1() __builtin_amdgcn_s_setprio(1)
#define PRIO0() __builtin_amdgcn_s_setprio(0)

#define DS_A(BUF, QM) do { \
    _Pragma("unroll") for (int mf = 0; mf < 4; ++mf) \
    _Pragma("unroll") for (int ks = 0; ks < 2; ++ks) \
        af[mf][ks] = *(const bf16x8*)&smem[(BUF)*16384 + wr*8192 + (((QM)*4+mf)*2+ks)*512 + lnb_e]; \
} while (0)

#define DS_B(BUF, QN, BB) do { \
    _Pragma("unroll") for (int nf = 0; nf < 2; ++nf) \
    _Pragma("unroll") for (int ks = 0; ks < 2; ++ks) \
        BB[nf][ks] = *(const bf16x8*)&smem[32768 + (BUF)*16384 + bhalf + (((QN)*2+nf)*2+ks)*512 + lnb_e]; \
} while (0)

#define MFMA_Q(QM, QN, BB) do { \
    _Pragma("unroll") for (int ks = 0; ks < 2; ++ks) \
    _Pragma("unroll") for (int mf = 0; mf < 4; ++mf) \
    _Pragma("unroll") for (int nf = 0; nf < 2; ++nf) \
        acc[(QM)*4+mf][(QN)*2+nf] = __builtin_amdgcn_mfma_f32_16x16x32_bf16( \
            af[mf][ks], BB[nf][ks], acc[(QM)*4+mf][(QN)*2+nf], 0, 0, 0); \
} while (0)

// stage one half-tile (128 rows x 64 k = 8192 elems): 2 x global_load_lds/thread
#define STAGE(GBASE, HROWS, TILE, EOFF) do { \
    gload_lds16((GBASE) + aoff0 + (size_t)(HROWS) * K + (TILE) * 64, \
                &smem[(EOFF) + wave * 512]); \
    gload_lds16((GBASE) + aoff1 + (size_t)(HROWS) * K + (TILE) * 64, \
                &smem[(EOFF) + 4096 + wave * 512]); \
} while (0)

template<bool GELU_EPI, int M, int N, int K>
__global__ __launch_bounds__(512, 2)
void gemm8r(const bf16_t* __restrict__ A, const bf16_t* __restrict__ BT,
            const float* __restrict__ bias, void* __restrict__ out)
{
    constexpr int BM = 256, BN = 256;
    constexpr int NT = K / 64, NI = NT / 2;
    constexpr int NBN = N / BN;
    __shared__ __align__(128) bf16_t smem[65536];   // 128 KiB

    const int t = threadIdx.x;
    const int wave = t >> 6, lane = t & 63;
    const int fr = lane & 15, fq = lane >> 4;
    const int wr = wave >> 2, wc = wave & 3;

    int wg = blockIdx.x;
    { const int cpx = (int)gridDim.x >> 3; wg = (wg & 7) * cpx + (wg >> 3); }
    const int bm = wg / NBN, bn = wg % NBN;
    const int rowA0 = bm * BM, colB0 = bn * BN;

    // staging source pre-swizzle (inverse st_16x32), proven rounds 4-7
    int sr0, sk0, sr1, sk1;
    {
        int o = t * 16;
        int ri = (o >> 6) & 15;
        int b = (o & 63) ^ ((ri & 8) << 2);
        sr0 = ((o >> 10) >> 1) * 16 + ri;
        sk0 = ((o >> 10) & 1) * 32 + (b >> 1);
        o = 8192 + t * 16;
        ri = (o >> 6) & 15;
        b = (o & 63) ^ ((ri & 8) << 2);
        sr1 = ((o >> 10) >> 1) * 16 + ri;
        sk1 = ((o >> 10) & 1) * 32 + (b >> 1);
    }
    const bf16_t* gA0 = A + (size_t)rowA0 * K;
    const bf16_t* gB0 = BT + (size_t)colB0 * K;
    const size_t aoff0 = (size_t)sr0 * K + sk0;
    const size_t aoff1 = (size_t)sr1 * K + sk1;

    // read-side swizzled lane base (elements): row fr, k-chunk fq
    const int lnb_e = fr * 32 + ((fq * 8) ^ ((fr & 8) << 1));
    const int bhalf = (wc >> 1) * 8192 + (wc & 1) * 4096;

    f32x4 acc[8][4] = {};
    bf16x8 af[4][2], b0[2][2], b1[2][2];

    // prologue: t0 fully + t1.A0/B0/B1; drain t0; pre-read B0(t0)
    STAGE(gA0, 0,   0, 0);          // t0.A0
    STAGE(gA0, 128, 0, 8192);       // t0.A1
    STAGE(gB0, 0,   0, 32768);      // t0.B0
    STAGE(gB0, 128, 0, 40960);      // t0.B1
    STAGE(gA0, 0,   1, 16384);      // t1.A0
    STAGE(gB0, 0,   1, 49152);      // t1.B0
    STAGE(gB0, 128, 1, 57344);      // t1.B1
    VMW(6);                         // t0 landed; t1's 6 loads in flight
    BAR();
    DS_B(0, 0, b0);                 // B0(t0) for P1/P4 (drained by P1's LGKM0)

    for (int i = 0; i < NI - 1; ++i) {
        const int t1 = 2 * i + 1, t2 = 2 * i + 2, t3 = 2 * i + 3;
        // P1: Q00 on buf0 | rd A-q0 {8}
        DS_A(0, 0);
        STAGE(gA0, 128, t1, 24576);            // buf1.A1 <- t1.A1
        BAR(); LGKM0();
        PRIO1(); MFMA_Q(0, 0, b0); PRIO0();
        BAR();
        // P2: Q01 | rd B1 {4}
        DS_B(0, 1, b1);
        BAR(); LGKM0();
        PRIO1(); MFMA_Q(0, 1, b1); PRIO0();
        BAR();
        // P3: Q11 | rd A-q1 {8} (buf0.B free after P2)
        DS_A(0, 1);
        STAGE(gB0, 0, t2, 32768);              // buf0.B0 <- t2.B0
        BAR(); LGKM0();
        PRIO1(); MFMA_Q(1, 1, b1); PRIO0();
        BAR();
        // P4: Q10 | post-cluster rd B0(t1) {4} into b0 (buf0.A free after P3)
        STAGE(gB0, 128, t2, 40960);            // buf0.B1 <- t2.B1
        STAGE(gA0, 0,   t2, 0);                // buf0.A0 <- t2.A0
        VMW(6);                                // all t1 landed
        BAR();
        PRIO1(); MFMA_Q(1, 0, b0); PRIO0();
        DS_B(1, 0, b0);                        // B0(t1); drained by P5's LGKM0
        BAR();
        // P5: Q00 on buf1 | rd A-q0 {8}
        DS_A(1, 0);
        STAGE(gA0, 128, t2, 8192);             // buf0.A1 <- t2.A1
        BAR(); LGKM0();
        PRIO1(); MFMA_Q(0, 0, b0); PRIO0();
        BAR();
        // P6: Q01 | rd B1 {4}
        DS_B(1, 1, b1);
        BAR(); LGKM0();
        PRIO1(); MFMA_Q(0, 1, b1); PRIO0();
        BAR();
        // P7: Q11 | rd A-q1 {8} (buf1.B free after P6)
        DS_A(1, 1);
        STAGE(gB0, 0, t3, 49152);              // buf1.B0 <- t3.B0
        BAR(); LGKM0();
        PRIO1(); MFMA_Q(1, 1, b1); PRIO0();
        BAR();
        // P8: Q10 | post-cluster rd B0(t2) {4} into b0 (buf1.A free after P7)
        STAGE(gB0, 128, t3, 57344);            // buf1.B1 <- t3.B1
        STAGE(gA0, 0,   t3, 16384);            // buf1.A0 <- t3.A0
        VMW(6);                                // all t2 landed
        BAR();
        PRIO1(); MFMA_Q(1, 0, b0); PRIO0();
        DS_B(0, 0, b0);                        // B0(t2); drained by next P1
        BAR();
    }

    // peeled last iteration: tiles NT-2 (buf0), NT-1 (buf1)
    // P1p
    DS_A(0, 0);
    STAGE(gA0, 128, NT - 1, 24576);            // buf1.A1 <- (NT-1).A1
    BAR(); LGKM0();
    PRIO1(); MFMA_Q(0, 0, b0); PRIO0();
    BAR();
    // P2p
    DS_B(0, 1, b1);
    BAR(); LGKM0();
    PRIO1(); MFMA_Q(0, 1, b1); PRIO0();
    BAR();
    // P3p
    DS_A(0, 1);
    BAR(); LGKM0();
    PRIO1(); MFMA_Q(1, 1, b1); PRIO0();
    BAR();
    // P4p: drain all; Q10; read B0(last tile)
    VMW(0);
    BAR();
    PRIO1(); MFMA_Q(1, 0, b0); PRIO0();
    DS_B(1, 0, b0);
    BAR();
    // P5p
    DS_A(1, 0);
    BAR(); LGKM0();
    PRIO1(); MFMA_Q(0, 0, b0); PRIO0();
    BAR();
    // P6p
    DS_B(1, 1, b1);
    BAR(); LGKM0();
    PRIO1(); MFMA_Q(0, 1, b1); PRIO0();
    BAR();
    // P7p
    DS_A(1, 1);
    BAR(); LGKM0();
    PRIO1(); MFMA_Q(1, 1, b1); PRIO0();
    // P8p (b0 drained at P5p)
    MFMA_Q(1, 0, b0);

    // epilogue: C/D layout col=lane&15, row=(lane>>4)*4+reg
    const int orow = rowA0 + wr * 128 + fq * 4;
    const int ocol = colB0 + wc * 64 + fr;
#pragma unroll
    for (int mf = 0; mf < 8; ++mf) {
#pragma unroll
        for (int nf = 0; nf < 4; ++nf) {
            const int c = ocol + nf * 16;
            const float bv = bias[c];
#pragma unroll
            for (int v = 0; v < 4; ++v) {
                const int r = orow + mf * 16 + v;
                float xv = acc[mf][nf][v] + bv;
                if constexpr (GELU_EPI) {
                    float g = 0.5f * xv * (1.0f + erff(xv * 0.70710678118654752f));
                    ((bf16_t*)out)[(size_t)r * N + c] = (bf16_t)g;
                } else {
                    ((float*)out)[(size_t)r * N + c] = xv;
                }
            }
        }
    }
}

extern "C" void kernel_launch(void* const* d_in, const int* in_sizes, int n_in,
                              void* d_out, int out_size, void* d_ws, size_t ws_size,
                              hipStream_t stream) {
    const float* x  = (const float*)d_in[0];
    const float* w1 = (const float*)d_in[1];
    const float* b1 = (const float*)d_in[2];
    const float* w2 = (const float*)d_in[3];
    const float* b2 = (const float*)d_in[4];
    float* y = (float*)d_out;

    const size_t xb_elems  = (size_t)TOKENS * HIDDEN;
    const size_t w1t_elems = (size_t)FFN * HIDDEN;
    const size_t w2t_elems = (size_t)HIDDEN * FFN;
    const size_t h_elems   = (size_t)TOKENS * FFN;
    const size_t need = (xb_elems + w1t_elems + w2t_elems + h_elems) * sizeof(bf16_t);
    if (ws_size < need) return;

    char* ws = (char*)d_ws;
    bf16_t* xb  = (bf16_t*)ws;
    bf16_t* w1t = xb + xb_elems;
    bf16_t* w2t = w1t + w1t_elems;
    bf16_t* h   = w2t + w2t_elems;

    cvt_f32_to_bf16<<<(TOKENS * HIDDEN / 8 + 255) / 256, 256, 0, stream>>>(
        x, xb, TOKENS * HIDDEN / 8);
    transpose_cvt<<<(HIDDEN / 64) * (FFN / 64), 256, 0, stream>>>(w1, w1t, HIDDEN, FFN);
    transpose_cvt<<<(FFN / 64) * (HIDDEN / 64), 256, 0, stream>>>(w2, w2t, FFN, HIDDEN);

    gemm8r<true, TOKENS, FFN, HIDDEN>
        <<<(TOKENS / 256) * (FFN / 256), 512, 0, stream>>>(xb, w1t, b1, h);
    gemm8r<false, TOKENS, HIDDEN, FFN>
        <<<(TOKENS / 256) * (HIDDEN / 256), 512, 0, stream>>>(h, w2t, b2, y);
}

// Round 11
// 1105.341 us; speedup vs baseline: 8.4453x; 1.0374x over previous
//
#include <hip/hip_runtime.h>
#include <hip/hip_bf16.h>
#include <cstdint>
#include <cstddef>

typedef __bf16 bf16_t;
typedef __bf16 bf16x8 __attribute__((ext_vector_type(8)));
typedef float  f32x4  __attribute__((ext_vector_type(4)));

#define TOKENS 16384
#define HIDDEN 2048
#define FFN    8192

__device__ __forceinline__ void gload_lds16(const bf16_t* g, bf16_t* l) {
    __builtin_amdgcn_global_load_lds((const __attribute__((address_space(1))) void*)g,
                                     (__attribute__((address_space(3))) void*)l,
                                     16, 0, 0);
}

__global__ void cvt_f32_to_bf16(const float* __restrict__ in, bf16_t* __restrict__ out, int n8) {
    int i = blockIdx.x * blockDim.x + threadIdx.x;
    if (i >= n8) return;
    size_t base = (size_t)i * 8;
    f32x4 v0 = *(const f32x4*)&in[base];
    f32x4 v1 = *(const f32x4*)&in[base + 4];
    bf16x8 o;
    o[0] = (bf16_t)v0[0]; o[1] = (bf16_t)v0[1]; o[2] = (bf16_t)v0[2]; o[3] = (bf16_t)v0[3];
    o[4] = (bf16_t)v1[0]; o[5] = (bf16_t)v1[1]; o[6] = (bf16_t)v1[2]; o[7] = (bf16_t)v1[3];
    *(bf16x8*)&out[base] = o;
}

__global__ void transpose_cvt(const float* __restrict__ src, bf16_t* __restrict__ dst,
                              int R, int C) {
    __shared__ bf16_t tile[64][66];
    const int tcols = C >> 6;
    const int bx = blockIdx.x % tcols;
    const int by = blockIdx.x / tcols;
    const int c0 = bx << 6, r0 = by << 6;
    const int t = threadIdx.x;
#pragma unroll
    for (int i = 0; i < 16; ++i) {
        int idx = i * 256 + t;
        int rr = idx >> 6, cc = idx & 63;
        tile[rr][cc] = (bf16_t)src[(size_t)(r0 + rr) * C + (c0 + cc)];
    }
    __syncthreads();
#pragma unroll
    for (int i = 0; i < 16; ++i) {
        int idx = i * 256 + t;
        int cc = idx >> 6, rr = idx & 63;
        dst[(size_t)(c0 + cc) * R + (r0 + rr)] = tile[rr][cc];
    }
}

// ---------------------------------------------------------------------------
// 256x256 8-phase GEMM == round-4 proven kernel with ONE deletion: all
// explicit lgkmcnt waits removed. The compiler's waitcnt pass inserts
// minimal COUNTED lgkmcnt(N) before each MFMA's first operand use, so MFMAs
// overlap the remaining LDS drain (m97-proven behavior) instead of our
// "memory"-clobbered wait-all serializing read-drain and MFMA.
//
// Correctness without explicit lgkm waits:
//  - RAW (ds_read -> MFMA): compiler value-tracks plain LDS loads; it emits
//    the required s_waitcnt before first use. (Rule #18 applies only to
//    inline-asm ds_reads; none here.)
//  - WAR (ds_read vs next STAGE overwrite): every region's reads are
//    consumed by MFMAs BEFORE the barrier preceding that region's overwrite
//    (R4 slot audit). MFMA issue implies operands returned; barriers order
//    the overwriting STAGE after all waves' consuming MFMAs.
//  - RAW (staged tile -> ds_read): guarded by VMW(6/0) with "memory"
//    (unchanged), which also blocks read hoisting above the vmcnt gate.
// LIVENESS + STAGE slots + vmcnt ledger: identical to round 4:
//   buf0.B free after P2, buf0.A after P3, buf1.B after P6, buf1.A after P7.
//   P1:t1.A1 | P3:t2.B0 | P4:t2.B1,t2.A0 | P5:t2.A1 | P7:t3.B0 | P8:t3.B1,t3.A0
//   entry P1 = 6 outstanding; P1:+2=8, P3:+2=10, P4:+4=14 -> VMW(6) = all t1;
//   P5:+2=8, P7:+2=10, P8:+4=14 -> VMW(6) = all t2.
// ---------------------------------------------------------------------------
#define BAR() __builtin_amdgcn_s_barrier()
#define VMW(n) asm volatile("s_waitcnt vmcnt(" #n ")" ::: "memory")
#define PRIO1() __builtin_amdgcn_s_setprio(1)
#define PRIO0() __builtin_amdgcn_s_setprio(0)

#define DS_A(BUF, QM) do { \
    _Pragma("unroll") for (int mf = 0; mf < 4; ++mf) \
    _Pragma("unroll") for (int ks = 0; ks < 2; ++ks) \
        af[mf][ks] = *(const bf16x8*)&smem[(BUF)*16384 + wr*8192 + (((QM)*4+mf)*2+ks)*512 + lnb_e]; \
} while (0)

#define DS_B(BUF, QN, BB) do { \
    _Pragma("unroll") for (int nf = 0; nf < 2; ++nf) \
    _Pragma("unroll") for (int ks = 0; ks < 2; ++ks) \
        BB[nf][ks] = *(const bf16x8*)&smem[32768 + (BUF)*16384 + bhalf + (((QN)*2+nf)*2+ks)*512 + lnb_e]; \
} while (0)

#define MFMA_Q(QM, QN, BB) do { \
    _Pragma("unroll") for (int ks = 0; ks < 2; ++ks) \
    _Pragma("unroll") for (int mf = 0; mf < 4; ++mf) \
    _Pragma("unroll") for (int nf = 0; nf < 2; ++nf) \
        acc[(QM)*4+mf][(QN)*2+nf] = __builtin_amdgcn_mfma_f32_16x16x32_bf16( \
            af[mf][ks], BB[nf][ks], acc[(QM)*4+mf][(QN)*2+nf], 0, 0, 0); \
} while (0)

// stage one half-tile (128 rows x 64 k = 8192 elems): 2 x global_load_lds/thread
#define STAGE(GBASE, HROWS, TILE, EOFF) do { \
    gload_lds16((GBASE) + aoff0 + (size_t)(HROWS) * K + (TILE) * 64, \
                &smem[(EOFF) + wave * 512]); \
    gload_lds16((GBASE) + aoff1 + (size_t)(HROWS) * K + (TILE) * 64, \
                &smem[(EOFF) + 4096 + wave * 512]); \
} while (0)

template<bool GELU_EPI, int M, int N, int K>
__global__ __launch_bounds__(512, 2)
void gemm8f(const bf16_t* __restrict__ A, const bf16_t* __restrict__ BT,
            const float* __restrict__ bias, void* __restrict__ out)
{
    constexpr int BM = 256, BN = 256;
    constexpr int NT = K / 64, NI = NT / 2;
    constexpr int NBN = N / BN;
    __shared__ __align__(128) bf16_t smem[65536];   // 128 KiB

    const int t = threadIdx.x;
    const int wave = t >> 6, lane = t & 63;
    const int fr = lane & 15, fq = lane >> 4;
    const int wr = wave >> 2, wc = wave & 3;

    int wg = blockIdx.x;
    { const int cpx = (int)gridDim.x >> 3; wg = (wg & 7) * cpx + (wg >> 3); }
    const int bm = wg / NBN, bn = wg % NBN;
    const int rowA0 = bm * BM, colB0 = bn * BN;

    // staging source pre-swizzle (inverse st_16x32), proven rounds 4-10
    int sr0, sk0, sr1, sk1;
    {
        int o = t * 16;
        int ri = (o >> 6) & 15;
        int b = (o & 63) ^ ((ri & 8) << 2);
        sr0 = ((o >> 10) >> 1) * 16 + ri;
        sk0 = ((o >> 10) & 1) * 32 + (b >> 1);
        o = 8192 + t * 16;
        ri = (o >> 6) & 15;
        b = (o & 63) ^ ((ri & 8) << 2);
        sr1 = ((o >> 10) >> 1) * 16 + ri;
        sk1 = ((o >> 10) & 1) * 32 + (b >> 1);
    }
    const bf16_t* gA0 = A + (size_t)rowA0 * K;
    const bf16_t* gB0 = BT + (size_t)colB0 * K;
    const size_t aoff0 = (size_t)sr0 * K + sk0;
    const size_t aoff1 = (size_t)sr1 * K + sk1;

    // read-side swizzled lane base (elements): row fr, k-chunk fq
    const int lnb_e = fr * 32 + ((fq * 8) ^ ((fr & 8) << 1));
    const int bhalf = (wc >> 1) * 8192 + (wc & 1) * 4096;

    f32x4 acc[8][4] = {};
    bf16x8 af[4][2], b0[2][2], b1[2][2];

    // prologue: t0 fully + t1.A0/B0/B1; drain t0
    STAGE(gA0, 0,   0, 0);          // t0.A0
    STAGE(gA0, 128, 0, 8192);       // t0.A1
    STAGE(gB0, 0,   0, 32768);      // t0.B0
    STAGE(gB0, 128, 0, 40960);      // t0.B1
    STAGE(gA0, 0,   1, 16384);      // t1.A0
    STAGE(gB0, 0,   1, 49152);      // t1.B0
    STAGE(gB0, 128, 1, 57344);      // t1.B1
    VMW(6);                         // t0 landed; t1's 6 loads in flight
    BAR();

    for (int i = 0; i < NI - 1; ++i) {
        const int t1 = 2 * i + 1, t2 = 2 * i + 2, t3 = 2 * i + 3;
        // P1: Q00 on buf0
        DS_A(0, 0); DS_B(0, 0, b0);
        STAGE(gA0, 128, t1, 24576);            // buf1.A1 <- t1.A1
        BAR();
        PRIO1(); MFMA_Q(0, 0, b0); PRIO0();
        BAR();
        // P2: Q01 (buf0.B live until end of P2)
        DS_B(0, 1, b1);
        BAR();
        PRIO1(); MFMA_Q(0, 1, b1); PRIO0();
        BAR();
        // P3: Q11 (buf0.B free after P2)
        DS_A(0, 1);
        STAGE(gB0, 0, t2, 32768);              // buf0.B0 <- t2.B0
        BAR();
        PRIO1(); MFMA_Q(1, 1, b1); PRIO0();
        BAR();
        // P4: Q10 regs-only (buf0.A free after P3)
        STAGE(gB0, 128, t2, 40960);            // buf0.B1 <- t2.B1
        STAGE(gA0, 0,   t2, 0);                // buf0.A0 <- t2.A0
        VMW(6);                                // all t1 landed
        BAR();
        PRIO1(); MFMA_Q(1, 0, b0); PRIO0();
        BAR();
        // P5: Q00 on buf1
        DS_A(1, 0); DS_B(1, 0, b0);
        STAGE(gA0, 128, t2, 8192);             // buf0.A1 <- t2.A1
        BAR();
        PRIO1(); MFMA_Q(0, 0, b0); PRIO0();
        BAR();
        // P6: Q01
        DS_B(1, 1, b1);
        BAR();
        PRIO1(); MFMA_Q(0, 1, b1); PRIO0();
        BAR();
        // P7: Q11 (buf1.B free after P6)
        DS_A(1, 1);
        STAGE(gB0, 0, t3, 49152);              // buf1.B0 <- t3.B0
        BAR();
        PRIO1(); MFMA_Q(1, 1, b1); PRIO0();
        BAR();
        // P8: Q10 (buf1.A free after P7)
        STAGE(gB0, 128, t3, 57344);            // buf1.B1 <- t3.B1
        STAGE(gA0, 0,   t3, 16384);            // buf1.A0 <- t3.A0
        VMW(6);                                // all t2 landed
        BAR();
        PRIO1(); MFMA_Q(1, 0, b0); PRIO0();
        BAR();
    }

    // peeled last iteration: tiles NT-2 (buf0), NT-1 (buf1)
    DS_A(0, 0); DS_B(0, 0, b0);
    STAGE(gA0, 128, NT - 1, 24576);            // buf1.A1 <- (NT-1).A1
    BAR();
    PRIO1(); MFMA_Q(0, 0, b0); PRIO0();
    BAR();
    DS_B(0, 1, b1);
    BAR();
    PRIO1(); MFMA_Q(0, 1, b1); PRIO0();
    BAR();
    DS_A(0, 1);
    BAR();
    PRIO1(); MFMA_Q(1, 1, b1); PRIO0();
    BAR();
    VMW(0);                                    // last tile fully landed
    BAR();
    PRIO1(); MFMA_Q(1, 0, b0); PRIO0();
    BAR();
    DS_A(1, 0); DS_B(1, 0, b0);
    BAR();
    PRIO1(); MFMA_Q(0, 0, b0); PRIO0();
    BAR();
    DS_B(1, 1, b1);
    BAR();
    PRIO1(); MFMA_Q(0, 1, b1); PRIO0();
    BAR();
    DS_A(1, 1);
    BAR();
    PRIO1(); MFMA_Q(1, 1, b1); PRIO0();
    MFMA_Q(1, 0, b0);

    // epilogue: C/D layout col=lane&15, row=(lane>>4)*4+reg
    const int orow = rowA0 + wr * 128 + fq * 4;
    const int ocol = colB0 + wc * 64 + fr;
#pragma unroll
    for (int mf = 0; mf < 8; ++mf) {
#pragma unroll
        for (int nf = 0; nf < 4; ++nf) {
            const int c = ocol + nf * 16;
            const float bv = bias[c];
#pragma unroll
            for (int v = 0; v < 4; ++v) {
                const int r = orow + mf * 16 + v;
                float xv = acc[mf][nf][v] + bv;
                if constexpr (GELU_EPI) {
                    float g = 0.5f * xv * (1.0f + erff(xv * 0.70710678118654752f));
                    ((bf16_t*)out)[(size_t)r * N + c] = (bf16_t)g;
                } else {
                    ((float*)out)[(size_t)r * N + c] = xv;
                }
            }
        }
    }
}

extern "C" void kernel_launch(void* const* d_in, const int* in_sizes, int n_in,
                              void* d_out, int out_size, void* d_ws, size_t ws_size,
                              hipStream_t stream) {
    const float* x  = (const float*)d_in[0];
    const float* w1 = (const float*)d_in[1];
    const float* b1 = (const float*)d_in[2];
    const float* w2 = (const float*)d_in[3];
    const float* b2 = (const float*)d_in[4];
    float* y = (float*)d_out;

    const size_t xb_elems  = (size_t)TOKENS * HIDDEN;
    const size_t w1t_elems = (size_t)FFN * HIDDEN;
    const size_t w2t_elems = (size_t)HIDDEN * FFN;
    const size_t h_elems   = (size_t)TOKENS * FFN;
    const size_t need = (xb_elems + w1t_elems + w2t_elems + h_elems) * sizeof(bf16_t);
    if (ws_size < need) return;

    char* ws = (char*)d_ws;
    bf16_t* xb  = (bf16_t*)ws;
    bf16_t* w1t = xb + xb_elems;
    bf16_t* w2t = w1t + w1t_elems;
    bf16_t* h   = w2t + w2t_elems;

    cvt_f32_to_bf16<<<(TOKENS * HIDDEN / 8 + 255) / 256, 256, 0, stream>>>(
        x, xb, TOKENS * HIDDEN / 8);
    transpose_cvt<<<(HIDDEN / 64) * (FFN / 64), 256, 0, stream>>>(w1, w1t, HIDDEN, FFN);
    transpose_cvt<<<(FFN / 64) * (HIDDEN / 64), 256, 0, stream>>>(w2, w2t, FFN, HIDDEN);

    gemm8f<true, TOKENS, FFN, HIDDEN>
        <<<(TOKENS / 256) * (FFN / 256), 512, 0, stream>>>(xb, w1t, b1, h);
    gemm8f<false, TOKENS, HIDDEN, FFN>
        <<<(TOKENS / 256) * (HIDDEN / 256), 512, 0, stream>>>(h, w2t, b2, y);
}